// Round 1
// 451.221 us; speedup vs baseline: 1.1561x; 1.1561x over previous
//
#include <hip/hip_runtime.h>
#include <cstdint>
#include <cstddef>

typedef __bf16 bf16_t;
typedef __bf16 bf16x8 __attribute__((ext_vector_type(8)));
typedef __bf16 bf16x4 __attribute__((ext_vector_type(4)));
typedef float  f32x4  __attribute__((ext_vector_type(4)));

#define HEADS    8
#define DIM_HEAD 64
#define SLICE    32
#define DIMC     512      // DIM == INNER == 512
#define NCOL     1024     // fused GEMM1 output cols: 8 heads x [q32|k32|v64]
#define BATCH    8
#define NSEQ     8192
#define NTOK     65536

// Async global->LDS, 16B per lane. LDS dest is wave-uniform base + lane*16.
__device__ __forceinline__ void gl2lds16(const bf16_t* g, bf16_t* l) {
  __builtin_amdgcn_global_load_lds(
      (const __attribute__((address_space(1))) uint32_t*)g,
      (__attribute__((address_space(3))) uint32_t*)l, 16, 0, 0);
}

// ---------------------------------------------------------------------------
// x fp32 -> bf16 (xb lives in d_out scratch; dead before GEMM3 writes out)
// ---------------------------------------------------------------------------
__global__ __launch_bounds__(256) void xcast_kernel(const float* __restrict__ x,
                                                    bf16_t* __restrict__ xb) {
  const size_t i = ((size_t)blockIdx.x * 256 + threadIdx.x) * 8;
  const float4 a = *reinterpret_cast<const float4*>(x + i);
  const float4 b = *reinterpret_cast<const float4*>(x + i + 4);
  bf16x8 w;
  w[0] = (bf16_t)a.x; w[1] = (bf16_t)a.y; w[2] = (bf16_t)a.z; w[3] = (bf16_t)a.w;
  w[4] = (bf16_t)b.x; w[5] = (bf16_t)b.y; w[6] = (bf16_t)b.z; w[7] = (bf16_t)b.w;
  *reinterpret_cast<bf16x8*>(xb + i) = w;
}

// ---------------------------------------------------------------------------
// Weight prep: WcT[col][cin] (bf16), NEW per-head column order:
//   col = h*128 + r;  r<32 -> Wq[:,r], r<64 -> Wk[:,r-32], else Wv[:,r-64]
// so that GEMM1 n-block nblk == head h holds q|k|v together (enables the
// fused kv outer-product epilogue).
// ---------------------------------------------------------------------------
__global__ __launch_bounds__(256) void wprep_kernel(
    const float* __restrict__ W_in, const float* __restrict__ b_in,
    const float* __restrict__ Wq,   const float* __restrict__ Wk,
    const float* __restrict__ Wv,
    bf16_t* __restrict__ WcT, float* __restrict__ bias_c) {
  __shared__ float sW[8192];                 // Wq[0..2048) Wk[2048..4096) Wv[4096..8192)
  for (int t = threadIdx.x; t < 2048; t += 256) { sW[t] = Wq[t]; sW[2048 + t] = Wk[t]; }
  for (int t = threadIdx.x; t < 4096; t += 256) sW[4096 + t] = Wv[t];
  __syncthreads();

  const int T  = blockIdx.x * 256 + threadIdx.x;
  const int NT = gridDim.x * 256;
  for (int idx = T; idx < NCOL * DIMC; idx += NT) {
    const int col = idx >> 9, cin = idx & 511;
    const int h = col >> 7, r = col & 127;
    int base, ldw, j;
    if (r < 32)      { j = r;      base = 0;    ldw = 32; }
    else if (r < 64) { j = r - 32; base = 2048; ldw = 32; }
    else             { j = r - 64; base = 4096; ldw = 64; }
    const float4* vp = reinterpret_cast<const float4*>(W_in + (size_t)cin * DIMC + h * DIM_HEAD);
    float acc = 0.f;
    #pragma unroll
    for (int d4 = 0; d4 < 16; ++d4) {
      const float4 v = vp[d4];
      acc += v.x * sW[base + (4*d4+0)*ldw + j];
      acc += v.y * sW[base + (4*d4+1)*ldw + j];
      acc += v.z * sW[base + (4*d4+2)*ldw + j];
      acc += v.w * sW[base + (4*d4+3)*ldw + j];
    }
    WcT[(size_t)col * DIMC + cin] = (bf16_t)acc;
  }
  if (T < NCOL) {
    const int col = T;
    const int h = col >> 7, r = col & 127;
    int base, ldw, j;
    if (r < 32)      { j = r;      base = 0;    ldw = 32; }
    else if (r < 64) { j = r - 32; base = 2048; ldw = 32; }
    else             { j = r - 64; base = 4096; ldw = 64; }
    const float* vec = b_in + h * DIM_HEAD;
    float acc = 0.f;
    #pragma unroll 8
    for (int d = 0; d < DIM_HEAD; ++d) acc += vec[d] * sW[base + d * ldw + j];
    bias_c[col] = acc;
  }
}

// ---------------------------------------------------------------------------
// 128x128xBK64 MFMA GEMM (m97 structure, XOR-swizzled unpadded LDS,
// global_load_lds 16B staging) + XCD-aware block swizzle.
// EPI=1 (GEMM1, per-head n-blocks): waves 0/1 hold q(32)+k(32) cols, waves
//   2/3 hold v(64) cols.  Fused epilogue:
//     q -> softmax over 32 cols -> bf16 q' [NTOK,256] (only HBM tile output)
//     k -> exp(+bias) -> bf16 into XOR-swizzled LDS (reuse As) + den reduce
//     v -> +bias -> bf16 into XOR-swizzled LDS (reuse Bs)
//   then all 4 waves: kv[32x64] = ek^T(32x128) @ v(128x64) via 8 MFMA/wave,
//   stored as non-atomic per-block f32 partial (mprep reduces 64 partials).
// EPI=0 (GEMM3): fp32 store + bias, batched via blockIdx.z.
// ---------------------------------------------------------------------------
template<int EPI>
__global__ __launch_bounds__(256) void gemm_kernel(
    const bf16_t* __restrict__ A, const bf16_t* __restrict__ Bt,
    void* __restrict__ Cv, const float* __restrict__ bias,
    int K, int lda, int ldc,
    size_t strideA, size_t strideB, size_t strideC,
    float* __restrict__ kvp_g, float* __restrict__ denp_g)
{
  __shared__ bf16_t As[128 * 64];   // unpadded: required by global_load_lds
  __shared__ bf16_t Bs[128 * 64];
  const int tid = threadIdx.x;
  // XCD swizzle: linear id p (x fastest); same-m group => same (p % 8).
  const int p = blockIdx.y * gridDim.x + blockIdx.x;
  int mblk, nblk;
  if (EPI == 1) { mblk = (p & 7) + ((p >> 6) << 3); nblk = (p >> 3) & 7; }
  else          { mblk = (p & 7) + ((p >> 5) << 3); nblk = (p >> 3) & 3; }
  const int m0 = mblk * 128;
  const int n0 = nblk * 128;
  const int bz = blockIdx.z;
  const int wave = tid >> 6, lane = tid & 63;
  const int cg   = lane & 15, qd = lane >> 4;
  const int wm   = (wave & 1) * 64, wn = (wave >> 1) * 64;
  const int srw    = lane >> 3;
  const int gchunk = (lane & 7) ^ srw;      // XOR column-chunk swizzle
  const int chb    = cg & 7;

  const bf16_t* Ab = A  + strideA * bz;
  const bf16_t* Bb = Bt + strideB * bz;

  f32x4 acc[4][4];
  #pragma unroll
  for (int i = 0; i < 4; ++i)
    #pragma unroll
    for (int j = 0; j < 4; ++j) acc[i][j] = (f32x4){0.f, 0.f, 0.f, 0.f};

  for (int k0 = 0; k0 < K; k0 += 64) {
    __syncthreads();
    #pragma unroll
    for (int i = 0; i < 4; ++i) {
      const int c = wave * 4 + i;
      const int row = c * 8 + srw;
      gl2lds16(Ab + (size_t)(m0 + row) * lda + k0 + gchunk * 8, As + c * 512 + lane * 8);
    }
    #pragma unroll
    for (int i = 0; i < 4; ++i) {
      const int c = wave * 4 + i;
      const int row = c * 8 + srw;
      gl2lds16(Bb + (size_t)(n0 + row) * K + k0 + gchunk * 8, Bs + c * 512 + lane * 8);
    }
    __syncthreads();
    #pragma unroll
    for (int ks = 0; ks < 64; ks += 32) {
      const int k4 = ks >> 3;
      bf16x8 af[4], bfr[4];
      #pragma unroll
      for (int i = 0; i < 4; ++i) {
        const int ch = (qd + k4) ^ chb;
        af[i] = *reinterpret_cast<const bf16x8*>(As + (wm + 16*i + cg) * 64 + ch * 8);
      }
      #pragma unroll
      for (int j = 0; j < 4; ++j) {
        const int ch = (qd + k4) ^ chb;
        bfr[j] = *reinterpret_cast<const bf16x8*>(Bs + (wn + 16*j + cg) * 64 + ch * 8);
      }
      #pragma unroll
      for (int i = 0; i < 4; ++i)
        #pragma unroll
        for (int j = 0; j < 4; ++j)
          acc[i][j] = __builtin_amdgcn_mfma_f32_16x16x32_bf16(af[i], bfr[j], acc[i][j], 0, 0, 0);
    }
  }

  if (EPI == 1) {
    const int h   = nblk;
    const int bat = mblk >> 6;        // 64 m-blocks per batch
    const int mb  = mblk & 63;
    const int bh  = bat * HEADS + h;
    __syncthreads();                   // all mainloop LDS reads done before reuse
    bf16_t* ekT   = As;                          // [32][128] bf16, XOR-swizzled, 8KB
    bf16_t* vT    = Bs;                          // [64][128] bf16, XOR-swizzled, 16KB
    float*  den_s = (float*)(void*)(As + 4096);  // bytes 8192..8447: [2][32] f32

    if (wave < 2) {
      // ---- q softmax over the head's 32 q cols (j=0,1); rows wm..wm+63 ----
      {
        const float b0 = bias[n0 + cg];
        const float b1 = bias[n0 + 16 + cg];
        #pragma unroll
        for (int i = 0; i < 4; ++i) {
          #pragma unroll
          for (int rr = 0; rr < 4; ++rr) {
            float v0 = acc[i][0][rr] + b0;
            float v1 = acc[i][1][rr] + b1;
            float mx = fmaxf(v0, v1);
            #pragma unroll
            for (int d = 1; d < 16; d <<= 1) mx = fmaxf(mx, __shfl_xor(mx, d, 64));
            const float e0 = __expf(v0 - mx), e1 = __expf(v1 - mx);
            float ssum = e0 + e1;
            #pragma unroll
            for (int d = 1; d < 16; d <<= 1) ssum += __shfl_xor(ssum, d, 64);
            const float rs = 1.f / ssum;
            const int row = m0 + wm + 16 * i + qd * 4 + rr;
            bf16_t* crow = (bf16_t*)Cv + (size_t)row * ldc + h * SLICE;
            crow[cg]      = (bf16_t)(e0 * rs);
            crow[16 + cg] = (bf16_t)(e1 * rs);
          }
        }
      }
      // ---- ek = exp(k + bias) (j=2,3) -> swizzled LDS + den partial ----
      #pragma unroll
      for (int j = 2; j < 4; ++j) {
        const int s = 16 * (j - 2) + cg;
        const float bb = bias[n0 + 16 * j + cg];
        float dsum = 0.f;
        #pragma unroll
        for (int i = 0; i < 4; ++i) {
          #pragma unroll
          for (int rr = 0; rr < 4; ++rr) {
            const float e = __expf(acc[i][j][rr] + bb);
            dsum += e;
            const int n = wm + 16 * i + qd * 4 + rr;
            *(bf16_t*)((char*)ekT + (((s << 8) + 2 * n) ^ ((s & 7) << 4))) = (bf16_t)e;
          }
        }
        dsum += __shfl_xor(dsum, 16, 64);   // reduce across qd group
        dsum += __shfl_xor(dsum, 32, 64);
        if (qd == 0) den_s[wave * 32 + s] = dsum;
      }
    } else {
      // ---- v + bias -> swizzled LDS (64 cols); rows wm..wm+63 ----
      #pragma unroll
      for (int j = 0; j < 4; ++j) {
        const int c = 16 * j + cg;
        const float bb = bias[n0 + 64 + c];
        #pragma unroll
        for (int i = 0; i < 4; ++i) {
          #pragma unroll
          for (int rr = 0; rr < 4; ++rr) {
            const float vv = acc[i][j][rr] + bb;
            const int n = wm + 16 * i + qd * 4 + rr;
            *(bf16_t*)((char*)vT + (((c << 8) + 2 * n) ^ ((c & 7) << 4))) = (bf16_t)vv;
          }
        }
      }
    }
    __syncthreads();
    if (tid < SLICE)
      denp_g[((size_t)bh * 64 + mb) * SLICE + tid] = den_s[tid] + den_s[32 + tid];

    // ---- kv outer product: kv[s][c] = sum_{n<128} ek[n][s] * v[n][c] ----
    // 8 output 16x16 tiles (2 s-tiles x 4 c-tiles), 2 per wave, K=128 (4 steps)
    const int st = wave & 1;
    const int sA = st * 16 + cg;
    float* kvp = kvp_g + ((size_t)bh * 64 + mb) * (SLICE * DIM_HEAD);
    #pragma unroll
    for (int ci = 0; ci < 2; ++ci) {
      const int ct = (wave >> 1) * 2 + ci;
      const int cB = ct * 16 + cg;
      f32x4 kacc = (f32x4){0.f, 0.f, 0.f, 0.f};
      #pragma unroll
      for (int ks = 0; ks < 4; ++ks) {
        bf16x8 afr = *(const bf16x8*)((const char*)ekT +
                       (((sA << 8) + ks * 64 + qd * 16) ^ ((sA & 7) << 4)));
        bf16x8 bfr2 = *(const bf16x8*)((const char*)vT +
                       (((cB << 8) + ks * 64 + qd * 16) ^ ((cB & 7) << 4)));
        kacc = __builtin_amdgcn_mfma_f32_16x16x32_bf16(afr, bfr2, kacc, 0, 0, 0);
      }
      #pragma unroll
      for (int r = 0; r < 4; ++r)
        kvp[(st * 16 + qd * 4 + r) * DIM_HEAD + ct * 16 + cg] = kacc[r];
    }
  } else {
    #pragma unroll
    for (int j = 0; j < 4; ++j) {
      const int col = n0 + wn + 16 * j + cg;
      const float bv = bias[col];
      #pragma unroll
      for (int i = 0; i < 4; ++i) {
        #pragma unroll
        for (int rr = 0; rr < 4; ++rr) {
          const int row = m0 + wm + 16 * i + qd * 4 + rr;
          ((float*)Cv + strideC * bz)[(size_t)row * ldc + col] = acc[i][j][rr] + bv;
        }
      }
    }
  }
}

// ---------------------------------------------------------------------------
// M prep: reduce 64 per-block kv/den partials, normalize, then
// Mt[b][outc][h*32+s] = sum_c kvn[s][c] * W_out[h*64+c][outc]
// ---------------------------------------------------------------------------
__global__ __launch_bounds__(512) void mprep_kernel(const float* __restrict__ kv_part,
                                                    const float* __restrict__ den_part,
                                                    const float* __restrict__ W_out,
                                                    bf16_t* __restrict__ Mt) {
  const int bh = blockIdx.x, bat = bh >> 3, h = bh & 7;
  const int tid = threadIdx.x;
  __shared__ float kvn[SLICE][DIM_HEAD];   // 8 KB (normalized kv)
  __shared__ float dsh[SLICE];
  __shared__ float wbuf[8][DIMC];          // 16 KB
  const float* np = kv_part + (size_t)bh * 64 * (SLICE * DIM_HEAD);
  if (tid < SLICE) {
    const float* dp = den_part + (size_t)bh * 64 * SLICE;
    float d = 0.f;
    for (int mb = 0; mb < 64; ++mb) d += dp[mb * SLICE + tid];
    dsh[tid] = d;
  }
  float a0 = 0.f, a1 = 0.f, a2 = 0.f, a3 = 0.f;
  for (int mb = 0; mb < 64; ++mb) {
    const float* qp = np + (size_t)mb * (SLICE * DIM_HEAD);
    a0 += qp[tid]; a1 += qp[tid + 512]; a2 += qp[tid + 1024]; a3 += qp[tid + 1536];
  }
  __syncthreads();
  kvn[tid >> 6][tid & 63]            = a0 / dsh[tid >> 6];
  kvn[(tid + 512) >> 6][tid & 63]    = a1 / dsh[(tid + 512) >> 6];
  kvn[(tid + 1024) >> 6][tid & 63]   = a2 / dsh[(tid + 1024) >> 6];
  kvn[(tid + 1536) >> 6][tid & 63]   = a3 / dsh[(tid + 1536) >> 6];

  float accs[SLICE];
  #pragma unroll
  for (int s = 0; s < SLICE; ++s) accs[s] = 0.f;
  for (int cb = 0; cb < DIM_HEAD; cb += 8) {
    __syncthreads();
    for (int t = tid; t < 8 * DIMC; t += 512)
      wbuf[t >> 9][t & 511] = W_out[(size_t)(h * DIM_HEAD + cb + (t >> 9)) * DIMC + (t & 511)];
    __syncthreads();
    #pragma unroll
    for (int cc = 0; cc < 8; ++cc) {
      const float wv = wbuf[cc][tid];
      #pragma unroll
      for (int s = 0; s < SLICE; ++s) accs[s] += kvn[s][cb + cc] * wv;
    }
  }
  bf16_t* dst = Mt + (size_t)bat * (DIMC * 256) + (size_t)tid * 256 + h * SLICE;
  #pragma unroll
  for (int s = 0; s < SLICE; ++s) dst[s] = (bf16_t)accs[s];
}

// ---------------------------------------------------------------------------
extern "C" void kernel_launch(void* const* d_in, const int* in_sizes, int n_in,
                              void* d_out, int out_size, void* d_ws, size_t ws_size,
                              hipStream_t stream) {
  const float* x     = (const float*)d_in[0];
  const float* W_in  = (const float*)d_in[1];
  const float* b_in  = (const float*)d_in[2];
  const float* Wq    = (const float*)d_in[3];
  const float* Wk    = (const float*)d_in[4];
  const float* Wv    = (const float*)d_in[5];
  const float* W_out = (const float*)d_in[6];
  const float* b_out = (const float*)d_in[7];

  uint8_t* ws = (uint8_t*)d_ws;
  bf16_t* qprime   = (bf16_t*)(ws);                     // 65536*256 bf16 = 33554432 B
  bf16_t* WcT      = (bf16_t*)(ws + 33554432ull);       // 1024*512 bf16  = 1048576 B
  float*  bias_c   = (float*) (ws + 34603008ull);       // 1024 f32       = 4096 B
  float*  kv_part  = (float*) (ws + 34607104ull);       // 64bh*64mb*2048 = 33554432 B
  float*  den_part = (float*) (ws + 68161536ull);       // 64*64*32 f32   = 524288 B
  bf16_t* Mt       = (bf16_t*)(ws + 68685824ull);       // 8*512*256 bf16 = 2097152 B
  // x_bf16 scratch lives in d_out (134 MB): dead before GEMM3 writes out.
  bf16_t* xb = (bf16_t*)d_out;                          // 65536*512 bf16 = 67108864 B

  xcast_kernel<<<dim3(NTOK * DIMC / 8 / 256), dim3(256), 0, stream>>>(x, xb);
  wprep_kernel<<<dim3(256), dim3(256), 0, stream>>>(W_in, b_in, Wq, Wk, Wv, WcT, bias_c);

  // GEMM1: xb [65536,512] @ WcT -> fused epilogue:
  //   q' [65536,256] bf16 + kv/den per-block partials (no expk/v to HBM)
  gemm_kernel<1><<<dim3(8, 512, 1), dim3(256), 0, stream>>>(
      xb, WcT, (void*)qprime, bias_c,
      512 /*K*/, 512 /*lda*/, 256 /*ldc*/, (size_t)0, (size_t)0, (size_t)0,
      kv_part, den_part);

  mprep_kernel<<<dim3(BATCH * HEADS), dim3(512), 0, stream>>>(kv_part, den_part, W_out, Mt);

  // GEMM3 (batched over b): q' [8192,256] bf16 @ Mt[b] -> out [8192,512] f32
  gemm_kernel<0><<<dim3(4, 64, BATCH), dim3(256), 0, stream>>>(
      qprime, Mt, d_out, b_out,
      256 /*K*/, 256 /*lda*/, DIMC /*ldc*/,
      (size_t)NSEQ * 256, (size_t)DIMC * 256, (size_t)NSEQ * DIMC,
      nullptr, nullptr);
}